// Round 4
// baseline (16.506 us; speedup 1.0000x reference)
//
#include <hip/hip_runtime.h>

#define BB 8
#define NN 1024
#define CLAMP_V 10.0f
#define UNCL_W 0.5f

// FAPE with orthonormal frames: t_i cancels in (pred_local - true_local) and
// R_i^T preserves norms, so diff(i,j) == ||pred_j - true_j||, independent of i.
//   total = sum_b (sum_i m_i) * (sum_j m_j * g(||pred_j - true_j||))
//   out   = total / (sum m + 1e-8)
// Single block, 1024 threads = 16 waves. Element data is consumed as quads
// (4 elements = 3 float4 loads), fully coalesced 16B/lane. Thread t handles
// quad t (batches 0..3) and quad t+1024 (batches 4..7); each wave's quads sit
// in a single batch per half, so per-batch sums reduce with wave shuffles.
__global__ __launch_bounds__(1024) void fape_fast_kernel(
    const float4* __restrict__ pred4, const float4* __restrict__ tru4,
    const int4* __restrict__ mask4, float* __restrict__ out)
{
    const int t = threadIdx.x;

    float gs[2], ms[2];
    gs[0] = gs[1] = ms[0] = ms[1] = 0.0f;

#pragma unroll
    for (int h = 0; h < 2; ++h) {
        const int q = t + h * 1024;            // quad index, 4 elements
        const float4 a0 = pred4[3 * q];
        const float4 a1 = pred4[3 * q + 1];
        const float4 a2 = pred4[3 * q + 2];
        const float4 b0 = tru4[3 * q];
        const float4 b1 = tru4[3 * q + 1];
        const float4 b2 = tru4[3 * q + 2];
        const int4  mm = mask4[q];

        float dx, dy, dz, diff, cl;

        dx = a0.x - b0.x; dy = a0.y - b0.y; dz = a0.z - b0.z;
        diff = sqrtf(dx * dx + dy * dy + dz * dz);
        cl = fminf(diff, CLAMP_V);
        const float g0 = cl + UNCL_W * (diff - cl);

        dx = a0.w - b0.w; dy = a1.x - b1.x; dz = a1.y - b1.y;
        diff = sqrtf(dx * dx + dy * dy + dz * dz);
        cl = fminf(diff, CLAMP_V);
        const float g1 = cl + UNCL_W * (diff - cl);

        dx = a1.z - b1.z; dy = a1.w - b1.w; dz = a2.x - b2.x;
        diff = sqrtf(dx * dx + dy * dy + dz * dz);
        cl = fminf(diff, CLAMP_V);
        const float g2 = cl + UNCL_W * (diff - cl);

        dx = a2.y - b2.y; dy = a2.z - b2.z; dz = a2.w - b2.w;
        diff = sqrtf(dx * dx + dy * dy + dz * dz);
        cl = fminf(diff, CLAMP_V);
        const float g3 = cl + UNCL_W * (diff - cl);

        const float m0 = mm.x ? 1.0f : 0.0f;
        const float m1 = mm.y ? 1.0f : 0.0f;
        const float m2 = mm.z ? 1.0f : 0.0f;
        const float m3 = mm.w ? 1.0f : 0.0f;

        gs[h] += g0 * m0 + g1 * m1 + g2 * m2 + g3 * m3;
        ms[h] += m0 + m1 + m2 + m3;
    }

    // Wave-level reduce of the 4 accumulators (64 lanes).
#pragma unroll
    for (int off = 32; off > 0; off >>= 1) {
        gs[0] += __shfl_down(gs[0], off, 64);
        ms[0] += __shfl_down(ms[0], off, 64);
        gs[1] += __shfl_down(gs[1], off, 64);
        ms[1] += __shfl_down(ms[1], off, 64);
    }

    __shared__ float sgl[16], sml[16], sgh[16], smh[16];
    __shared__ float prod[8], msb[8];
    const int wid = t >> 6;
    if ((t & 63) == 0) {
        sgl[wid] = gs[0]; sml[wid] = ms[0];   // batch  wid>>2
        sgh[wid] = gs[1]; smh[wid] = ms[1];   // batch (wid>>2)+4
    }
    __syncthreads();

    if (t < 8) {
        float Sg, Sm;
        if (t < 4) {
            const int base = 4 * t;
            Sg = sgl[base] + sgl[base + 1] + sgl[base + 2] + sgl[base + 3];
            Sm = sml[base] + sml[base + 1] + sml[base + 2] + sml[base + 3];
        } else {
            const int base = 4 * (t - 4);
            Sg = sgh[base] + sgh[base + 1] + sgh[base + 2] + sgh[base + 3];
            Sm = smh[base] + smh[base + 1] + smh[base + 2] + smh[base + 3];
        }
        prod[t] = Sg * Sm;   // (sum_i m_i) * (sum_j m_j g_j) for batch t
        msb[t] = Sm;
    }
    __syncthreads();

    if (t == 0) {
        float tot = 0.0f, mt = 0.0f;
#pragma unroll
        for (int i = 0; i < 8; ++i) { tot += prod[i]; mt += msb[i]; }
        out[0] = tot / (mt + 1e-8f);
    }
}

extern "C" void kernel_launch(void* const* d_in, const int* in_sizes, int n_in,
                              void* d_out, int out_size, void* d_ws, size_t ws_size,
                              hipStream_t stream) {
    // inputs: n, ca, c, pred_pos, true_pos, mask — frames unused (norm-invariance).
    const float4* pred_p = (const float4*)d_in[3];
    const float4* true_p = (const float4*)d_in[4];
    const int4* mask_p   = (const int4*)d_in[5];
    float* out = (float*)d_out;

    fape_fast_kernel<<<1, 1024, 0, stream>>>(pred_p, true_p, mask_p, out);
}

// Round 6
// 10.901 us; speedup vs baseline: 1.5142x; 1.5142x over previous
//
#include <hip/hip_runtime.h>

#define BB 8
#define NN 1024
#define CLAMP_V 10.0f
#define UNCL_W 0.5f

// FAPE with orthonormal frames: t_i cancels in (pred_local - true_local) and
// R_i^T preserves norms, so diff(i,j) == ||pred_j - true_j||, independent of i:
//   total = sum_b (sum_i m_i) * (sum_j m_j * g(||pred_j - true_j||))
//   out   = total / (sum m + 1e-8)
// k1: 8 blocks (one per batch) x 256 threads; thread t owns quad q=b*256+t
// (4 elements = 48B contiguous): 3 float4 pred + 3 float4 true + 1 int4 mask.
// Wave shuffle + LDS reduce -> ws[2b]=Sg_b, ws[2b+1]=Sm_b (plain overwrite,
// no zeroing needed, deterministic).
// k2: single tiny block combines the 16 partials in fixed order.
__global__ __launch_bounds__(256) void fape_partial_kernel(
    const float4* __restrict__ pred4, const float4* __restrict__ tru4,
    const int4* __restrict__ mask4, float* __restrict__ ws)
{
    const int b = blockIdx.x;     // batch 0..7
    const int t = threadIdx.x;    // 0..255
    const int q = b * 256 + t;    // global quad index (4 elements)

    const float4 a0 = pred4[3 * q];
    const float4 a1 = pred4[3 * q + 1];
    const float4 a2 = pred4[3 * q + 2];
    const float4 b0 = tru4[3 * q];
    const float4 b1 = tru4[3 * q + 1];
    const float4 b2 = tru4[3 * q + 2];
    const int4  mm = mask4[q];

    float dx, dy, dz, diff, cl;

    dx = a0.x - b0.x; dy = a0.y - b0.y; dz = a0.z - b0.z;
    diff = sqrtf(dx * dx + dy * dy + dz * dz);
    cl = fminf(diff, CLAMP_V);
    const float g0 = cl + UNCL_W * (diff - cl);

    dx = a0.w - b0.w; dy = a1.x - b1.x; dz = a1.y - b1.y;
    diff = sqrtf(dx * dx + dy * dy + dz * dz);
    cl = fminf(diff, CLAMP_V);
    const float g1 = cl + UNCL_W * (diff - cl);

    dx = a1.z - b1.z; dy = a1.w - b1.w; dz = a2.x - b2.x;
    diff = sqrtf(dx * dx + dy * dy + dz * dz);
    cl = fminf(diff, CLAMP_V);
    const float g2 = cl + UNCL_W * (diff - cl);

    dx = a2.y - b2.y; dy = a2.z - b2.z; dz = a2.w - b2.w;
    diff = sqrtf(dx * dx + dy * dy + dz * dz);
    cl = fminf(diff, CLAMP_V);
    const float g3 = cl + UNCL_W * (diff - cl);

    const float m0 = mm.x ? 1.0f : 0.0f;
    const float m1 = mm.y ? 1.0f : 0.0f;
    const float m2 = mm.z ? 1.0f : 0.0f;
    const float m3 = mm.w ? 1.0f : 0.0f;

    float gs = g0 * m0 + g1 * m1 + g2 * m2 + g3 * m3;
    float ms = m0 + m1 + m2 + m3;

#pragma unroll
    for (int off = 32; off > 0; off >>= 1) {
        gs += __shfl_down(gs, off, 64);
        ms += __shfl_down(ms, off, 64);
    }

    __shared__ float sg[4], sm[4];
    const int wid = t >> 6;
    if ((t & 63) == 0) { sg[wid] = gs; sm[wid] = ms; }
    __syncthreads();

    if (t == 0) {
        const float Sg = sg[0] + sg[1] + sg[2] + sg[3];
        const float Sm = sm[0] + sm[1] + sm[2] + sm[3];
        ws[2 * b]     = Sg;
        ws[2 * b + 1] = Sm;
    }
}

__global__ __launch_bounds__(64) void fape_final_kernel(
    const float* __restrict__ ws, float* __restrict__ out)
{
    if (threadIdx.x == 0) {
        float tot = 0.0f, mt = 0.0f;
#pragma unroll
        for (int i = 0; i < BB; ++i) {
            const float Sg = ws[2 * i];
            const float Sm = ws[2 * i + 1];
            tot += Sg * Sm;
            mt += Sm;
        }
        out[0] = tot / (mt + 1e-8f);
    }
}

extern "C" void kernel_launch(void* const* d_in, const int* in_sizes, int n_in,
                              void* d_out, int out_size, void* d_ws, size_t ws_size,
                              hipStream_t stream) {
    // inputs: n, ca, c, pred_pos, true_pos, mask — frames unused (norm-invariance).
    const float4* pred_p = (const float4*)d_in[3];
    const float4* true_p = (const float4*)d_in[4];
    const int4* mask_p   = (const int4*)d_in[5];
    float* out = (float*)d_out;
    float* ws = (float*)d_ws;

    fape_partial_kernel<<<BB, 256, 0, stream>>>(pred_p, true_p, mask_p, ws);
    fape_final_kernel<<<1, 64, 0, stream>>>(ws, out);
}